// Round 15
// baseline (126.525 us; speedup 1.0000x reference)
//
#include <hip/hip_runtime.h>

#define B_ 256
#define L_ 512
#define D_ 768
#define C_ 10331
#define K_ 2304           // 3*D
#define NT 32             // W rows (out cols) per block
#define NBLK 323          // ceil(C_/NT)
#define NSUP 9            // K supers of 256 fp32 (1KB per row per super)

using v8bf = __attribute__((ext_vector_type(8))) __bf16;
using v4f  = __attribute__((ext_vector_type(4))) float;

__device__ __forceinline__ unsigned short f2bf(float f) {
    unsigned int u = __float_as_uint(f);
    unsigned int r = (u + 0x7FFFu + ((u >> 16) & 1u)) >> 16;   // RNE
    return (unsigned short)r;
}

__device__ __forceinline__ void fma4(float4& a, float w, const float4& v) {
    a.x = fmaf(w, v.x, a.x); a.y = fmaf(w, v.y, a.y);
    a.z = fmaf(w, v.z, a.z); a.w = fmaf(w, v.w, a.w);
}

__device__ __forceinline__ void gload_lds16(const void* g, void* l) {
    __builtin_amdgcn_global_load_lds(
        (const __attribute__((address_space(1))) void*)g,
        (__attribute__((address_space(3))) void*)l, 16, 0, 0);
}

// ---------------------------------------------------------------------------
// Kernel 1: count-based gather + masked means -> feats (B, 3D) bf16.
// (unchanged; ~13 us)
// ---------------------------------------------------------------------------
__global__ __launch_bounds__(512) void feats_gather(
    const float* __restrict__ seq,        // (B, L, D)
    const int*   __restrict__ head_index, // (B, L)
    const int*   __restrict__ start,
    const int*   __restrict__ end,
    unsigned short* __restrict__ feats)   // (B, 3D) bf16
{
    const int b    = blockIdx.x;
    const int t    = threadIdx.x;
    const int lane = t & 63;
    const int wave = t >> 6;              // 0..7

    __shared__ int idx_sh[L_];
    __shared__ int cnt_sh[3][L_];
    __shared__ int list_sh[L_];
    __shared__ int nz_sh, nlist_sh;
    __shared__ float4 red_sh[8][3][192];  // 72 KB

    if (t == 0) nz_sh = 0;
    cnt_sh[0][t] = 0; cnt_sh[1][t] = 0; cnt_sh[2][t] = 0;
    const int v = head_index[b * L_ + t];
    idx_sh[t] = v;
    unsigned long long ball = __ballot(v != 0);
    __syncthreads();
    if (lane == 0) atomicAdd(&nz_sh, (int)__popcll(ball));
    __syncthreads();

    const int right_len = nz_sh;
    const int s = start[b];
    const int e = end[b];

    if (t < right_len) {
        int r = (t < s) ? 0 : ((t < e) ? 1 : 2);
        atomicAdd(&cnt_sh[r][v], 1);
    }
    __syncthreads();

    if (wave == 0) {
        int maskbits = 0, csum = 0;
        const int j0 = lane * 8;
        #pragma unroll
        for (int k = 0; k < 8; ++k) {
            int j = j0 + k;
            if (cnt_sh[0][j] | cnt_sh[1][j] | cnt_sh[2][j]) { maskbits |= (1 << k); ++csum; }
        }
        int incl = csum;
        #pragma unroll
        for (int off = 1; off < 64; off <<= 1) {
            int x = __shfl_up(incl, off, 64);
            if (lane >= off) incl += x;
        }
        int pos = incl - csum;
        #pragma unroll
        for (int k = 0; k < 8; ++k)
            if (maskbits & (1 << k)) list_sh[pos++] = j0 + k;
        if (lane == 63) nlist_sh = incl;
    }
    __syncthreads();

    const int nlist = nlist_sh;
    const int nl = s, nm = e - s, nr = right_len - e;
    const float rs0 = (nl > 0) ? 1.0f / (float)nl : 0.0f;
    const float rs1 = (nm > 0) ? 1.0f / (float)nm : 0.0f;
    const float rs2 = (nr > 0) ? 1.0f / (float)nr : 0.0f;

    const float4* seqb4 = reinterpret_cast<const float4*>(seq + (size_t)b * L_ * D_);

    float4 acc[3][3];
    #pragma unroll
    for (int r = 0; r < 3; ++r)
        #pragma unroll
        for (int jj = 0; jj < 3; ++jj)
            acc[r][jj] = make_float4(0.f, 0.f, 0.f, 0.f);

    int i = wave;
    for (; i + 8 < nlist; i += 16) {
        const int ja = list_sh[i], jb = list_sh[i + 8];
        const float4* rowa = seqb4 + (size_t)ja * 192;
        const float4* rowb = seqb4 + (size_t)jb * 192;
        float wa0 = (float)cnt_sh[0][ja] * rs0;
        float wa1 = (float)cnt_sh[1][ja] * rs1;
        float wa2 = (float)cnt_sh[2][ja] * rs2;
        float wb0 = (float)cnt_sh[0][jb] * rs0;
        float wb1 = (float)cnt_sh[1][jb] * rs1;
        float wb2 = (float)cnt_sh[2][jb] * rs2;
        #pragma unroll
        for (int jj = 0; jj < 3; ++jj) {
            float4 va = rowa[jj * 64 + lane];
            float4 vb = rowb[jj * 64 + lane];
            fma4(acc[0][jj], wa0, va); fma4(acc[1][jj], wa1, va); fma4(acc[2][jj], wa2, va);
            fma4(acc[0][jj], wb0, vb); fma4(acc[1][jj], wb1, vb); fma4(acc[2][jj], wb2, vb);
        }
    }
    if (i < nlist) {
        const int ja = list_sh[i];
        const float4* rowa = seqb4 + (size_t)ja * 192;
        float wa0 = (float)cnt_sh[0][ja] * rs0;
        float wa1 = (float)cnt_sh[1][ja] * rs1;
        float wa2 = (float)cnt_sh[2][ja] * rs2;
        #pragma unroll
        for (int jj = 0; jj < 3; ++jj) {
            float4 va = rowa[jj * 64 + lane];
            fma4(acc[0][jj], wa0, va); fma4(acc[1][jj], wa1, va); fma4(acc[2][jj], wa2, va);
        }
    }

    #pragma unroll
    for (int r = 0; r < 3; ++r)
        #pragma unroll
        for (int jj = 0; jj < 3; ++jj)
            red_sh[wave][r][jj * 64 + lane] = acc[r][jj];
    __syncthreads();

    for (int w = t; w < 576; w += 512) {
        int reg = w / 192, pos = w - reg * 192;
        float4 sum = red_sh[0][reg][pos];
        #pragma unroll
        for (int wv = 1; wv < 8; ++wv) {
            float4 x = red_sh[wv][reg][pos];
            sum.x += x.x; sum.y += x.y; sum.z += x.z; sum.w += x.w;
        }
        ushort4 u;
        u.x = f2bf(sum.x); u.y = f2bf(sum.y); u.z = f2bf(sum.z); u.w = f2bf(sum.w);
        *(ushort4*)(&feats[(size_t)b * K_ + reg * D_ + pos * 4]) = u;
    }
}

// ---------------------------------------------------------------------------
// Kernel 2: out = feats(bf16) @ W^T + bias, full K, direct write.
// Block = 32 W-rows x 256 batch; 512 thr, 8 waves each owning 32 batch rows
// (m=2 frags), all waves compute all 32 cols (n=2). K in 9 supers of 256:
// each super stages 32KB of W via 4 gll/wave, each gll = one contiguous 1KB
// row-segment (DRAM-friendly). LDS slot == W-tile row (FIX from r14: dest
// base is (wave + i*8)*1024, matching the read's row*1024 indexing).
// Issue order per super s:
//   [vmcnt(20): retire gll(s)] [barrier] [compute(s): af-waits bottom at
//   vmcnt(4), W stream never fully drained] [LOAD_AF(s+1)] [barrier]
//   [gll(s+2)] — af loads are older than the gll they must not drain
//   (m135 oldest-first semantics).
// W LDS XOR-swizzled (both sides): ~4-way conflicts. A-frags direct from L2.
// ---------------------------------------------------------------------------
__global__ __launch_bounds__(512, 4) void mfma_gemm(
    const unsigned short* __restrict__ A,  // (B_, K_) bf16
    const float* __restrict__ W,           // (C_, K_) fp32
    const float* __restrict__ bias,        // (C_,)
    float*       __restrict__ out)         // (B_, C_) f32
{
    __shared__ float Ws0[NT * 256];   // 32 KB
    __shared__ float Ws1[NT * 256];   // 32 KB

    const int t    = threadIdx.x;
    const int lane = t & 63;
    const int wave = t >> 6;          // 0..7
    const int frow = lane & 15;
    const int q    = lane >> 4;       // 0..3

    // bijective XCD swizzle (m204), nwg=323: q=40, r=3
    const int orig = blockIdx.x;
    const int xcd  = orig & 7;
    const int pp   = orig >> 3;
    const int swb  = (xcd < 3 ? xcd * 41 : 123 + (xcd - 3) * 40) + pp;
    const int col0 = swb * NT;

    const unsigned short* a_base = A + (size_t)(wave * 32 + frow) * K_ + q * 8;
    const char* Wb = (const char*)W;

    // staging: wave handles tile-rows {wave, wave+8, wave+16, wave+24};
    // lane covers the row's 1KB in address order, source pre-XOR-swizzled.
    size_t srcoff[4];
    #pragma unroll
    for (int i = 0; i < 4; ++i) {
        int row = wave + i * 8;
        int gr  = col0 + row; if (gr > C_ - 1) gr = C_ - 1;
        srcoff[i] = (size_t)gr * (K_ * 4) + (size_t)((lane * 16) ^ ((row & 15) << 4));
    }

    v4f  acc[2][2] = {};
    v8bf af[2][8];

#define STAGE(BUF, S) { \
        _Pragma("unroll") \
        for (int i = 0; i < 4; ++i) \
            gload_lds16(Wb + (size_t)(S) * 1024 + srcoff[i], \
                        (char*)(BUF) + (wave + i * 8) * 1024); }

#define LOAD_AF(S) { \
        _Pragma("unroll") \
        for (int m = 0; m < 2; ++m) \
            _Pragma("unroll") \
            for (int kk = 0; kk < 8; ++kk) \
                af[m][kk] = *(const v8bf*)(a_base + (size_t)m * 16 * K_ + (S) * 256 + kk * 32); }

#define COMPUTE(BUF) { \
        _Pragma("unroll") \
        for (int st = 0; st < 4; ++st) { \
            v8bf bfr[2][2]; \
            _Pragma("unroll") \
            for (int n = 0; n < 2; ++n) { \
                int row = n * 16 + frow; \
                int sw  = (row & 15) << 4; \
                const char* rb = (const char*)(BUF) + row * 1024; \
                _Pragma("unroll") \
                for (int kk = 0; kk < 2; ++kk) { \
                    int off = st * 256 + kk * 128 + q * 32; \
                    float4 lo = *(const float4*)(rb + (off ^ sw)); \
                    float4 hi = *(const float4*)(rb + (off ^ 16 ^ sw)); \
                    v8bf bv; \
                    bv[0] = (__bf16)lo.x; bv[1] = (__bf16)lo.y; \
                    bv[2] = (__bf16)lo.z; bv[3] = (__bf16)lo.w; \
                    bv[4] = (__bf16)hi.x; bv[5] = (__bf16)hi.y; \
                    bv[6] = (__bf16)hi.z; bv[7] = (__bf16)hi.w; \
                    bfr[n][kk] = bv; } } \
            _Pragma("unroll") \
            for (int kk = 0; kk < 2; ++kk) \
                _Pragma("unroll") \
                for (int m = 0; m < 2; ++m) \
                    _Pragma("unroll") \
                    for (int n = 0; n < 2; ++n) \
                        acc[m][n] = __builtin_amdgcn_mfma_f32_16x16x32_bf16(af[m][st * 2 + kk], bfr[n][kk], acc[m][n], 0, 0, 0); } }

    // prologue: af(0) oldest, then gll(0), gll(1)  [24 outstanding]
    LOAD_AF(0)
    STAGE(Ws0, 0)
    STAGE(Ws1, 1)

    #pragma unroll
    for (int s = 0; s < NSUP; ++s) {
        if (s == 0)            { asm volatile("s_waitcnt vmcnt(4)"  ::: "memory"); }
        else if (s == NSUP - 1){ asm volatile("s_waitcnt vmcnt(16)" ::: "memory"); }
        else                   { asm volatile("s_waitcnt vmcnt(20)" ::: "memory"); }
        __builtin_amdgcn_s_barrier();
        __builtin_amdgcn_sched_barrier(0);
        if (s & 1) { COMPUTE(Ws1) } else { COMPUTE(Ws0) }
        __builtin_amdgcn_sched_barrier(0);
        if (s + 1 < NSUP) { LOAD_AF(s + 1) }          // older than gll(s+2)
        __builtin_amdgcn_sched_barrier(0);
        __builtin_amdgcn_s_barrier();                 // all reads of buf done
        __builtin_amdgcn_sched_barrier(0);
        if (s + 2 < NSUP) { if (s & 1) { STAGE(Ws1, s + 2) } else { STAGE(Ws0, s + 2) } }
        __builtin_amdgcn_sched_barrier(0);
    }

    // ---- epilogue: direct out + bias ----
    const int crow = wave * 32 + q * 4;
    const int ccol = col0 + frow;
    #pragma unroll
    for (int n = 0; n < 2; ++n) {
        int col = ccol + n * 16;
        if (col < C_) {
            float bv = bias[col];
            #pragma unroll
            for (int m = 0; m < 2; ++m)
                #pragma unroll
                for (int r = 0; r < 4; ++r)
                    out[(size_t)(crow + m * 16 + r) * C_ + col] = acc[m][n][r] + bv;
        }
    }
#undef STAGE
#undef LOAD_AF
#undef COMPUTE
}

// ---------------------------------------------------------------------------
extern "C" void kernel_launch(void* const* d_in, const int* in_sizes, int n_in,
                              void* d_out, int out_size, void* d_ws, size_t ws_size,
                              hipStream_t stream) {
    const float* seq        = (const float*)d_in[0];
    const int*   head_index = (const int*)  d_in[1];
    const int*   start      = (const int*)  d_in[2];
    const int*   end        = (const int*)  d_in[3];
    const float* W          = (const float*)d_in[4];
    const float* bias       = (const float*)d_in[5];
    float*       out        = (float*)d_out;

    unsigned short* feats = (unsigned short*)d_ws;   // 1.18 MB

    feats_gather<<<dim3(B_), dim3(512), 0, stream>>>(seq, head_index, start, end, feats);
    mfma_gemm<<<dim3(NBLK), dim3(512), 0, stream>>>(feats, W, bias, out);
}

// Round 16
// 107.074 us; speedup vs baseline: 1.1817x; 1.1817x over previous
//
#include <hip/hip_runtime.h>

#define B_ 256
#define L_ 512
#define D_ 768
#define C_ 10331
#define K_ 2304           // 3*D
#define NT 32             // out cols (W rows) per block
#define NBLK 323          // ceil(C_/NT)
#define GBK 64
#define NKIT (K_ / GBK)   // 36

using v8bf = __attribute__((ext_vector_type(8))) __bf16;
using v4f  = __attribute__((ext_vector_type(4))) float;

__device__ __forceinline__ unsigned short f2bf(float f) {
    unsigned int u = __float_as_uint(f);
    unsigned int r = (u + 0x7FFFu + ((u >> 16) & 1u)) >> 16;   // RNE
    return (unsigned short)r;
}

__device__ __forceinline__ void fma4(float4& a, float w, const float4& v) {
    a.x = fmaf(w, v.x, a.x); a.y = fmaf(w, v.y, a.y);
    a.z = fmaf(w, v.z, a.z); a.w = fmaf(w, v.w, a.w);
}

// ---------------------------------------------------------------------------
// Kernel 1: count-based gather + masked means -> feats (B, 3D) bf16.
// (unchanged; ~13 us)
// ---------------------------------------------------------------------------
__global__ __launch_bounds__(512) void feats_gather(
    const float* __restrict__ seq,        // (B, L, D)
    const int*   __restrict__ head_index, // (B, L)
    const int*   __restrict__ start,
    const int*   __restrict__ end,
    unsigned short* __restrict__ feats)   // (B, 3D) bf16
{
    const int b    = blockIdx.x;
    const int t    = threadIdx.x;
    const int lane = t & 63;
    const int wave = t >> 6;              // 0..7

    __shared__ int idx_sh[L_];
    __shared__ int cnt_sh[3][L_];
    __shared__ int list_sh[L_];
    __shared__ int nz_sh, nlist_sh;
    __shared__ float4 red_sh[8][3][192];  // 72 KB

    if (t == 0) nz_sh = 0;
    cnt_sh[0][t] = 0; cnt_sh[1][t] = 0; cnt_sh[2][t] = 0;
    const int v = head_index[b * L_ + t];
    idx_sh[t] = v;
    unsigned long long ball = __ballot(v != 0);
    __syncthreads();
    if (lane == 0) atomicAdd(&nz_sh, (int)__popcll(ball));
    __syncthreads();

    const int right_len = nz_sh;
    const int s = start[b];
    const int e = end[b];

    if (t < right_len) {
        int r = (t < s) ? 0 : ((t < e) ? 1 : 2);
        atomicAdd(&cnt_sh[r][v], 1);
    }
    __syncthreads();

    if (wave == 0) {
        int maskbits = 0, csum = 0;
        const int j0 = lane * 8;
        #pragma unroll
        for (int k = 0; k < 8; ++k) {
            int j = j0 + k;
            if (cnt_sh[0][j] | cnt_sh[1][j] | cnt_sh[2][j]) { maskbits |= (1 << k); ++csum; }
        }
        int incl = csum;
        #pragma unroll
        for (int off = 1; off < 64; off <<= 1) {
            int x = __shfl_up(incl, off, 64);
            if (lane >= off) incl += x;
        }
        int pos = incl - csum;
        #pragma unroll
        for (int k = 0; k < 8; ++k)
            if (maskbits & (1 << k)) list_sh[pos++] = j0 + k;
        if (lane == 63) nlist_sh = incl;
    }
    __syncthreads();

    const int nlist = nlist_sh;
    const int nl = s, nm = e - s, nr = right_len - e;
    const float rs0 = (nl > 0) ? 1.0f / (float)nl : 0.0f;
    const float rs1 = (nm > 0) ? 1.0f / (float)nm : 0.0f;
    const float rs2 = (nr > 0) ? 1.0f / (float)nr : 0.0f;

    const float4* seqb4 = reinterpret_cast<const float4*>(seq + (size_t)b * L_ * D_);

    float4 acc[3][3];
    #pragma unroll
    for (int r = 0; r < 3; ++r)
        #pragma unroll
        for (int jj = 0; jj < 3; ++jj)
            acc[r][jj] = make_float4(0.f, 0.f, 0.f, 0.f);

    int i = wave;
    for (; i + 8 < nlist; i += 16) {
        const int ja = list_sh[i], jb = list_sh[i + 8];
        const float4* rowa = seqb4 + (size_t)ja * 192;
        const float4* rowb = seqb4 + (size_t)jb * 192;
        float wa0 = (float)cnt_sh[0][ja] * rs0;
        float wa1 = (float)cnt_sh[1][ja] * rs1;
        float wa2 = (float)cnt_sh[2][ja] * rs2;
        float wb0 = (float)cnt_sh[0][jb] * rs0;
        float wb1 = (float)cnt_sh[1][jb] * rs1;
        float wb2 = (float)cnt_sh[2][jb] * rs2;
        #pragma unroll
        for (int jj = 0; jj < 3; ++jj) {
            float4 va = rowa[jj * 64 + lane];
            float4 vb = rowb[jj * 64 + lane];
            fma4(acc[0][jj], wa0, va); fma4(acc[1][jj], wa1, va); fma4(acc[2][jj], wa2, va);
            fma4(acc[0][jj], wb0, vb); fma4(acc[1][jj], wb1, vb); fma4(acc[2][jj], wb2, vb);
        }
    }
    if (i < nlist) {
        const int ja = list_sh[i];
        const float4* rowa = seqb4 + (size_t)ja * 192;
        float wa0 = (float)cnt_sh[0][ja] * rs0;
        float wa1 = (float)cnt_sh[1][ja] * rs1;
        float wa2 = (float)cnt_sh[2][ja] * rs2;
        #pragma unroll
        for (int jj = 0; jj < 3; ++jj) {
            float4 va = rowa[jj * 64 + lane];
            fma4(acc[0][jj], wa0, va); fma4(acc[1][jj], wa1, va); fma4(acc[2][jj], wa2, va);
        }
    }

    #pragma unroll
    for (int r = 0; r < 3; ++r)
        #pragma unroll
        for (int jj = 0; jj < 3; ++jj)
            red_sh[wave][r][jj * 64 + lane] = acc[r][jj];
    __syncthreads();

    for (int w = t; w < 576; w += 512) {
        int reg = w / 192, pos = w - reg * 192;
        float4 sum = red_sh[0][reg][pos];
        #pragma unroll
        for (int wv = 1; wv < 8; ++wv) {
            float4 x = red_sh[wv][reg][pos];
            sum.x += x.x; sum.y += x.y; sum.z += x.z; sum.w += x.w;
        }
        ushort4 u;
        u.x = f2bf(sum.x); u.y = f2bf(sum.y); u.z = f2bf(sum.z); u.w = f2bf(sum.w);
        *(ushort4*)(&feats[(size_t)b * K_ + reg * D_ + pos * 4]) = u;
    }
}

// ---------------------------------------------------------------------------
// Kernel 2: out = feats(bf16) @ W^T + bias — full K per block, direct write.
// Block = 32 out-cols x 256 batch; 512 thr, 8 waves (wave owns 32 batch rows,
// m=2; all waves share the 32 cols, n=2). Each W row read ONCE, sequentially
// (9KB contiguous). Simple r10-proven schedule: per phase {WRITE_B; sync;
// LOAD_AF(next); LOAD_B(+3); COMPUTE} — compiler emits counted vmcnt (A
// issued before W each phase keeps the W stream in flight). 3-deep W reg
// slots, 2 XOR-swizzled LDS buffers, no hand asm. grid 323, ~2 blocks/CU.
// ---------------------------------------------------------------------------
__global__ __launch_bounds__(512, 4) void mfma_gemm(
    const unsigned short* __restrict__ A,  // (B_, K_) bf16
    const float* __restrict__ W,           // (C_, K_) fp32
    const float* __restrict__ bias,        // (C_,)
    float*       __restrict__ out)         // (B_, C_) f32
{
    __shared__ char Bs0[NT * 128];   // 4 KB (32 rows x 64 bf16)
    __shared__ char Bs1[NT * 128];   // 4 KB

    const int t    = threadIdx.x;
    const int lane = t & 63;
    const int wave = t >> 6;          // 0..7
    const int frow = lane & 15;
    const int q    = lane >> 4;       // 0..3
    const int col0 = blockIdx.x * NT;

    // staging coords: thread t covers (row = t>>4, 16B chunk = t&15)
    const int sr   = t >> 4;          // 0..31
    const int sc   = t & 15;
    int gr = col0 + sr; if (gr > C_ - 1) gr = C_ - 1;
    const float* wrow = W + (size_t)gr * K_ + sc * 4;
    const int wb8 = (sc * 8) ^ ((sr & 7) << 4);   // swizzled 8B dest in row

    const unsigned short* a_base = A + (size_t)(wave * 32 + frow) * K_ + q * 8;

    v4f  acc[2][2] = {};
    v8bf afA[2][2], afB[2][2];
    float4 rb0, rb1, rb2;

#define LOAD_B(DST, IT) { DST = *(const float4*)(wrow + (IT) * GBK); }

#define WRITE_B(BUF, SRC) { \
        ushort4 u_; \
        u_.x = f2bf(SRC.x); u_.y = f2bf(SRC.y); \
        u_.z = f2bf(SRC.z); u_.w = f2bf(SRC.w); \
        *(ushort4*)((BUF) + sr * 128 + wb8) = u_; }

#define LOAD_AF(DST, IT) { \
        _Pragma("unroll") \
        for (int m_ = 0; m_ < 2; ++m_) \
            _Pragma("unroll") \
            for (int kk_ = 0; kk_ < 2; ++kk_) \
                DST[m_][kk_] = *(const v8bf*)(a_base + (size_t)m_ * 16 * K_ + (IT) * GBK + kk_ * 32); }

#define COMPUTE(AF, BUF) { \
        v8bf bfr[2][2]; \
        _Pragma("unroll") \
        for (int n_ = 0; n_ < 2; ++n_) { \
            int row_ = n_ * 16 + frow; \
            int sw_  = (row_ & 7) << 4; \
            _Pragma("unroll") \
            for (int kk_ = 0; kk_ < 2; ++kk_) \
                bfr[n_][kk_] = *(const v8bf*)((BUF) + row_ * 128 + ((kk_ * 64 + q * 16) ^ sw_)); } \
        _Pragma("unroll") \
        for (int kk_ = 0; kk_ < 2; ++kk_) \
            _Pragma("unroll") \
            for (int m_ = 0; m_ < 2; ++m_) \
                _Pragma("unroll") \
                for (int n_ = 0; n_ < 2; ++n_) \
                    acc[m_][n_] = __builtin_amdgcn_mfma_f32_16x16x32_bf16(AF[m_][kk_], bfr[n_][kk_], acc[m_][n_], 0, 0, 0); }

    // prologue: A first (oldest), then 3 W slots
    LOAD_AF(afA, 0)
    LOAD_B(rb0, 0) LOAD_B(rb1, 1) LOAD_B(rb2, 2)

    #pragma unroll
    for (int it = 0; it < NKIT; ++it) {
        char* buf = (it & 1) ? Bs1 : Bs0;
        if      ((it % 3) == 0) { WRITE_B(buf, rb0) }
        else if ((it % 3) == 1) { WRITE_B(buf, rb1) }
        else                    { WRITE_B(buf, rb2) }
        __syncthreads();
        if ((it & 1) == 0) { if (it + 1 < NKIT) LOAD_AF(afB, it + 1) }
        else               { if (it + 1 < NKIT) LOAD_AF(afA, it + 1) }
        if (it + 3 < NKIT) {
            if      ((it % 3) == 0) { LOAD_B(rb0, it + 3) }
            else if ((it % 3) == 1) { LOAD_B(rb1, it + 3) }
            else                    { LOAD_B(rb2, it + 3) }
        }
        if ((it & 1) == 0) { COMPUTE(afA, buf) }
        else               { COMPUTE(afB, buf) }
    }

    // ---- epilogue: direct out + bias ----
    const int crow = wave * 32 + q * 4;
    const int ccol = col0 + frow;
    #pragma unroll
    for (int n = 0; n < 2; ++n) {
        int col = ccol + n * 16;
        if (col < C_) {
            float bv = bias[col];
            #pragma unroll
            for (int m = 0; m < 2; ++m)
                #pragma unroll
                for (int r = 0; r < 4; ++r)
                    out[(size_t)(crow + m * 16 + r) * C_ + col] = acc[m][n][r] + bv;
        }
    }
#undef LOAD_B
#undef WRITE_B
#undef LOAD_AF
#undef COMPUTE
}

// ---------------------------------------------------------------------------
extern "C" void kernel_launch(void* const* d_in, const int* in_sizes, int n_in,
                              void* d_out, int out_size, void* d_ws, size_t ws_size,
                              hipStream_t stream) {
    const float* seq        = (const float*)d_in[0];
    const int*   head_index = (const int*)  d_in[1];
    const int*   start      = (const int*)  d_in[2];
    const int*   end        = (const int*)  d_in[3];
    const float* W          = (const float*)d_in[4];
    const float* bias       = (const float*)d_in[5];
    float*       out        = (float*)d_out;

    unsigned short* feats = (unsigned short*)d_ws;   // 1.18 MB

    feats_gather<<<dim3(B_), dim3(512), 0, stream>>>(seq, head_index, start, end, feats);
    mfma_gemm<<<dim3(NBLK), dim3(512), 0, stream>>>(feats, W, bias, out);
}